// Round 1
// 2209.721 us; speedup vs baseline: 1.1656x; 1.1656x over previous
//
#include <hip/hip_runtime.h>
#include <hip/hip_bf16.h>
#include <math.h>

#define NNODES 100000
#define FIN    2613
#define KENC   2624      // FIN padded to multiple of 32
#define HID    256
#define NEDGE  320000
#define NLAYER 4
#define STEP_F 0.1f
#define EPS_F  1e-5f
#define NB1    391       // ceil(NNODES/256) scan blocks

typedef unsigned short u16;
typedef __bf16 bf16_8 __attribute__((ext_vector_type(8)));
typedef float  f32x4v __attribute__((ext_vector_type(4)));

static __device__ __forceinline__ u16 f2bf(float f) {
    unsigned int u; __builtin_memcpy(&u, &f, 4);
    unsigned int r = (u + 0x7fffu + ((u >> 16) & 1u)) >> 16;
    return (u16)r;
}
static __device__ __forceinline__ float bf2f(u16 u) {
    unsigned int i = ((unsigned int)u) << 16;
    float f; __builtin_memcpy(&f, &i, 4);
    return f;
}

static __device__ __forceinline__ void async4(void* l, const void* g) {
    __builtin_amdgcn_global_load_lds((const __attribute__((address_space(1))) unsigned int*)g,
                                     (__attribute__((address_space(3))) unsigned int*)l, 4, 0, 0);
}
static __device__ __forceinline__ void async16(void* l, const void* g) {
    __builtin_amdgcn_global_load_lds((const __attribute__((address_space(1))) unsigned int*)g,
                                     (__attribute__((address_space(3))) unsigned int*)l, 16, 0, 0);
}

// ---------------------------------------------------------------------------
// GEMM: C[M x 256] = A[M x K] * B[256 x K]^T   (B given n-major, bf16)
// Tile: 128(M) x 256(N) per block, 256 threads (4 waves, each 128x64).
// STAGE: 0 = A f32, rows NOT 16B-aligned (dword global_load_lds, k-clamped)
//        1 = A f32, ldA%4==0, K%32==0 (16B global_load_lds)
//        2 = A bf16 (16B global_load_lds)
// MODE:  0 = store f32   1 = store bf16   2 = +bias, elu, store bf16
//        3 = +bias, store f32
//        4 = store f32 + accumulate per-column sum/sumsq into bias[0..511]
//            (fused BN statistics: bias is a non-const float[512] scratch)
// ---------------------------------------------------------------------------
template<int STAGE, int MODE>
__global__ __launch_bounds__(256, 2) void gemm_n256(
    const void* __restrict__ Av, const u16* __restrict__ B, void* __restrict__ Cv,
    const float* __restrict__ bias, int M, int ldA, int ldB, int KT, int kmaxA)
{
    constexpr int ABYTES = (STAGE == 2) ? 8192 : 16384;
    __shared__ __align__(16) unsigned char lds[ABYTES + 16384];
    unsigned char* As = lds;
    unsigned char* Bs = lds + ABYTES;

    const int tid  = threadIdx.x;
    const int wave = tid >> 6;
    const int lane = tid & 63;
    const int mblock = blockIdx.x * 128;

    f32x4v acc[8][4];
#pragma unroll
    for (int i = 0; i < 8; ++i)
#pragma unroll
        for (int j = 0; j < 4; ++j)
            acc[i][j] = (f32x4v){0.f, 0.f, 0.f, 0.f};

    for (int kt = 0; kt < KT; ++kt) {
        __syncthreads();
        // ---- stage A ----
        if (STAGE == 0) {
            const float* A = (const float*)Av;
#pragma unroll
            for (int c = 0; c < 16; ++c) {
                int idx = c * 256 + tid;          // dword position in [128][32]
                int row = idx >> 5;
                int kq  = (idx >> 2) & 7;
                int kl  = idx & 3;
                int ksrc = ((kq ^ (row & 7)) << 2) | kl;   // swizzled source k
                int grow = mblock + row; if (grow > M - 1) grow = M - 1;
                int gk = kt * 32 + ksrc; if (gk > kmaxA - 1) gk = kmaxA - 1;
                async4(As + (size_t)(c * 256 + wave * 64) * 4,
                       A + (size_t)grow * ldA + gk);
            }
        } else if (STAGE == 1) {
            const float* A = (const float*)Av;
#pragma unroll
            for (int c = 0; c < 4; ++c) {
                int idx4 = c * 256 + tid;         // 16B group in [128][32] f32
                int row = idx4 >> 3;
                int q   = idx4 & 7;
                int qsrc = q ^ (row & 7);
                int grow = mblock + row; if (grow > M - 1) grow = M - 1;
                async16(As + (size_t)(c * 256 + wave * 64) * 16,
                        A + (size_t)grow * ldA + kt * 32 + qsrc * 4);
            }
        } else {
            const u16* A = (const u16*)Av;
#pragma unroll
            for (int c = 0; c < 2; ++c) {
                int idx8 = c * 256 + tid;         // 16B group in [128][32] bf16
                int row = idx8 >> 2;
                int ch  = idx8 & 3;
                int csrc = ch ^ (row & 3);
                int grow = mblock + row; if (grow > M - 1) grow = M - 1;
                async16(As + (size_t)(c * 256 + wave * 64) * 16,
                        A + (size_t)grow * ldA + kt * 32 + csrc * 8);
            }
        }
        // ---- stage B: [256][32] bf16 ----
#pragma unroll
        for (int c = 0; c < 4; ++c) {
            int idx8 = c * 256 + tid;
            int n  = idx8 >> 2;
            int ch = idx8 & 3;
            int csrc = ch ^ (n & 3);
            async16(Bs + (size_t)(c * 256 + wave * 64) * 16,
                    B + (size_t)n * ldB + kt * 32 + csrc * 8);
        }
        __syncthreads();

        // ---- compute ----
        bf16_8 bfr[4];
#pragma unroll
        for (int j = 0; j < 4; ++j) {
            int n = wave * 64 + j * 16 + (lane & 15);
            int ch = (lane >> 4) ^ (n & 3);
            bfr[j] = *(const bf16_8*)(Bs + (size_t)n * 64 + (size_t)ch * 16);
        }
#pragma unroll
        for (int i = 0; i < 8; ++i) {
            bf16_8 af;
            int row = i * 16 + (lane & 15);
            if (STAGE == 2) {
                int ch = (lane >> 4) ^ (row & 3);
                af = *(const bf16_8*)(As + (size_t)row * 64 + (size_t)ch * 16);
            } else {
                int kq0 = (lane >> 4) * 2;
                f32x4v a0 = *(const f32x4v*)(As + (size_t)row * 128 + (size_t)((kq0    ) ^ (row & 7)) * 16);
                f32x4v a1 = *(const f32x4v*)(As + (size_t)row * 128 + (size_t)((kq0 + 1) ^ (row & 7)) * 16);
                af[0] = (__bf16)a0[0]; af[1] = (__bf16)a0[1]; af[2] = (__bf16)a0[2]; af[3] = (__bf16)a0[3];
                af[4] = (__bf16)a1[0]; af[5] = (__bf16)a1[1]; af[6] = (__bf16)a1[2]; af[7] = (__bf16)a1[3];
            }
#pragma unroll
            for (int j = 0; j < 4; ++j)
                acc[i][j] = __builtin_amdgcn_mfma_f32_16x16x32_bf16(af, bfr[j], acc[i][j], 0, 0, 0);
        }
    }

    // ---- epilogue ----
#pragma unroll
    for (int j = 0; j < 4; ++j) {
        int col = wave * 64 + j * 16 + (lane & 15);
        float bv = 0.f;
        if (MODE == 2 || MODE == 3) bv = bias[col];
        float s = 0.f, q = 0.f;
#pragma unroll
        for (int i = 0; i < 8; ++i) {
            int rowb = mblock + i * 16 + ((lane >> 4) << 2);
#pragma unroll
            for (int r = 0; r < 4; ++r) {
                int row = rowb + r;
                if (row < M) {
                    float v = acc[i][j][r];
                    if (MODE == 0) {
                        ((float*)Cv)[(size_t)row * 256 + col] = v;
                    } else if (MODE == 1) {
                        ((u16*)Cv)[(size_t)row * 256 + col] = f2bf(v);
                    } else if (MODE == 2) {
                        v += bv; v = (v > 0.f) ? v : expm1f(v);
                        ((u16*)Cv)[(size_t)row * 256 + col] = f2bf(v);
                    } else if (MODE == 3) {
                        ((float*)Cv)[(size_t)row * 256 + col] = v + bv;
                    } else {
                        ((float*)Cv)[(size_t)row * 256 + col] = v;
                        s += v; q += v * v;
                    }
                }
            }
        }
        if (MODE == 4) {
            // lanes {l, l^16, l^32, l^48} hold the 4 row-group partials of col
            s += __shfl_xor(s, 16, 64); s += __shfl_xor(s, 32, 64);
            q += __shfl_xor(q, 16, 64); q += __shfl_xor(q, 32, 64);
            if ((lane & 48) == 0) {
                atomicAdd(const_cast<float*>(&bias[col]),       s);
                atomicAdd(const_cast<float*>(&bias[col + 256]), q);
            }
        }
    }
}

// ---------------------------------------------------------------------------
// small prep kernels
// ---------------------------------------------------------------------------
__global__ void conv_encw(const float* __restrict__ w, u16* __restrict__ o) {
    int i = blockIdx.x * 256 + threadIdx.x;      // over 256*KENC
    int n = i / KENC, k = i - n * KENC;
    float v = (k < FIN) ? w[(size_t)n * FIN + k] : 0.f;
    o[i] = f2bf(v);
}

__global__ void conv_w256(const float* __restrict__ w1, const float* __restrict__ w2,
                          u16* __restrict__ o1, u16* __restrict__ o2) {
    int i = blockIdx.x * 256 + threadIdx.x;      // 512 blocks
    if (i < 65536) o1[i] = f2bf(w1[i]);
    else           o2[i - 65536] = f2bf(w2[i - 65536]);
}

// one row per block, 256 blocks (was 1 serial block)
__global__ void make_wp(const float* __restrict__ pw, u16* __restrict__ wp) {
    const int i = blockIdx.x;
    const int j = threadIdx.x;
    const int lane = j & 63, wid = j >> 6;
    __shared__ float ws4[4];
    __shared__ float ssum;
    float w0;
    if (i < j)      w0 = pw[i * 258 + j];
    else if (i > j) w0 = pw[j * 258 + i];
    else            w0 = 0.f;
    float a = fabsf(w0);
#pragma unroll
    for (int off = 32; off > 0; off >>= 1) a += __shfl_xor(a, off, 64);
    if (lane == 0) ws4[wid] = a;
    __syncthreads();
    if (j == 0) ssum = ws4[0] + ws4[1] + ws4[2] + ws4[3];
    __syncthreads();
    if (j != i) {
        wp[i * 256 + j] = f2bf(w0);
    } else {
        float q = pw[i * 258 + 256];
        float r = pw[i * 258 + 257];
        wp[i * 256 + i] = f2bf(q * ssum + r);
    }
}

__global__ void count_deg(const int* __restrict__ ei, int* __restrict__ deg) {
    int e = blockIdx.x * 256 + threadIdx.x;
    if (e < NEDGE) atomicAdd(&deg[ei[NEDGE + e]], 1);
}

// ---- parallel 3-phase scan over deg (replaces serial single-block scan) ----
__global__ void scan_pass1(const int* __restrict__ deg, int* __restrict__ bsum) {
    __shared__ int ws4[4];
    const int t = threadIdx.x, lane = t & 63, wid = t >> 6;
    int i = blockIdx.x * 256 + t;
    int v = (i < NNODES) ? deg[i] : 0;
#pragma unroll
    for (int off = 32; off > 0; off >>= 1) v += __shfl_xor(v, off, 64);
    if (lane == 0) ws4[wid] = v;
    __syncthreads();
    if (t == 0) bsum[blockIdx.x] = ws4[0] + ws4[1] + ws4[2] + ws4[3];
}

__global__ void scan_pass2(int* __restrict__ bsum) {   // 1 block, 512 threads
    __shared__ int wsum[8];
    const int t = threadIdx.x, lane = t & 63, wid = t >> 6;
    int v = (t < NB1) ? bsum[t] : 0;
    int s = v;
#pragma unroll
    for (int off = 1; off < 64; off <<= 1) {
        int x = __shfl_up(s, off, 64);
        if (lane >= off) s += x;
    }
    if (lane == 63) wsum[wid] = s;
    __syncthreads();
    int woff = 0;
    for (int w = 0; w < wid; ++w) woff += wsum[w];
    if (t < NB1) bsum[t] = woff + s;                    // inclusive block sums
}

__global__ void scan_pass3(const int* __restrict__ deg, const int* __restrict__ bsum,
                           int* __restrict__ rowptr, int* __restrict__ fillp,
                           float* __restrict__ dinv) {
    __shared__ int wsum[4];
    const int b = blockIdx.x, t = threadIdx.x, lane = t & 63, wid = t >> 6;
    int i = b * 256 + t;
    int v = (i < NNODES) ? deg[i] : 0;
    int s = v;
#pragma unroll
    for (int off = 1; off < 64; off <<= 1) {
        int x = __shfl_up(s, off, 64);
        if (lane >= off) s += x;
    }
    if (lane == 63) wsum[wid] = s;
    __syncthreads();
    int woff = 0;
    for (int w = 0; w < wid; ++w) woff += wsum[w];
    int off0 = (b > 0) ? bsum[b - 1] : 0;
    int incl = off0 + woff + s;
    if (i < NNODES) {
        rowptr[i + 1] = incl;
        fillp[i]      = incl - v;                       // exclusive = rowptr[i]
        dinv[i]       = (v > 0) ? (1.0f / sqrtf((float)v)) : 0.f;
    }
    if (b == 0 && t == 0) rowptr[0] = 0;
}

// edges interleaved: {src_node, bits(norm_weight)} — one 8B record per edge
__global__ void fill_csr(const int* __restrict__ ei, const float* __restrict__ dinv,
                         int* __restrict__ fillpos, int2* __restrict__ edges) {
    int e = blockIdx.x * 256 + threadIdx.x;
    if (e < NEDGE) {
        int r = ei[e], c = ei[NEDGE + e];
        int pos = atomicAdd(&fillpos[c], 1);
        edges[pos] = make_int2(r, __float_as_int(dinv[r] * dinv[c]));
    }
}

// ---------------------------------------------------------------------------
// batchnorm finish + apply (stats now fused into encoder GEMM epilogue)
// ---------------------------------------------------------------------------
__global__ void bn_final(const float* __restrict__ sums, const float* __restrict__ gamma,
                         const float* __restrict__ beta, float* __restrict__ ss) {
    int c = threadIdx.x;
    float mean = sums[c] * (1.f / NNODES);
    float var  = sums[256 + c] * (1.f / NNODES) - mean * mean;
    float sc   = gamma[c] / sqrtf(var + EPS_F);
    ss[c] = sc;
    ss[256 + c] = beta[c] - mean * sc;
}

__global__ void bn_apply(float* __restrict__ h, float* __restrict__ h0,
                         const float* __restrict__ ss) {
    size_t i = (size_t)blockIdx.x * 256 + threadIdx.x;   // float4 group
    int cg = (int)(i & 63);
    float4 v  = ((const float4*)h)[i];
    float4 sc = ((const float4*)ss)[cg];
    float4 sh = ((const float4*)(ss + 256))[cg];
    v.x = v.x * sc.x + sh.x;
    v.y = v.y * sc.y + sh.y;
    v.z = v.z * sc.z + sh.z;
    v.w = v.w * sc.w + sh.w;
    ((float4*)h)[i]  = v;
    ((float4*)h0)[i] = v;
}

// ---------------------------------------------------------------------------
// graph aggregation + GRAFF update (one wave per node)
// Edge records prefetched lane-parallel (one coalesced load covers the whole
// adjacency list for deg<=64), broadcast via shfl — removes the per-edge
// dependent load->load chain so the 512B row gathers pipeline.
// ---------------------------------------------------------------------------
__global__ void layer_agg(const u16* __restrict__ outp, const int* __restrict__ rowptr,
                          const int2* __restrict__ edges,
                          const float* __restrict__ extw, const float* __restrict__ srcb,
                          const float* __restrict__ h0, float* __restrict__ h) {
    int gw   = (blockIdx.x * 256 + threadIdx.x) >> 6;    // node id
    int lane = threadIdx.x & 63;
    if (gw >= NNODES) return;
    int beg = rowptr[gw], end = rowptr[gw + 1];
    int n   = end - beg;
    float a0 = 0.f, a1 = 0.f, a2 = 0.f, a3 = 0.f;
    if (n <= 64) {
        int2 e = (lane < n) ? edges[beg + lane] : make_int2(0, 0);
        for (int k = 0; k < n; ++k) {
            int   s = __shfl(e.x, k, 64);
            float w = __int_as_float(__shfl(e.y, k, 64));
            ushort4 u = ((const ushort4*)(outp + (size_t)s * 256))[lane];
            a0 += w * bf2f(u.x);
            a1 += w * bf2f(u.y);
            a2 += w * bf2f(u.z);
            a3 += w * bf2f(u.w);
        }
    } else {
        for (int i = beg; i < end; ++i) {
            int2 e = edges[i];
            float w = __int_as_float(e.y);
            ushort4 u = ((const ushort4*)(outp + (size_t)e.x * 256))[lane];
            a0 += w * bf2f(u.x);
            a1 += w * bf2f(u.y);
            a2 += w * bf2f(u.z);
            a3 += w * bf2f(u.w);
        }
    }
    float4 hv  = ((const float4*)h )[(size_t)gw * 64 + lane];
    float4 h0v = ((const float4*)h0)[(size_t)gw * 64 + lane];
    float4 ew  = ((const float4*)extw)[lane];
    float  sb  = srcb[0];
    float o0 = a0 - hv.x * ew.x - sb * h0v.x;
    float o1 = a1 - hv.y * ew.y - sb * h0v.y;
    float o2 = a2 - hv.z * ew.z - sb * h0v.z;
    float o3 = a3 - hv.w * ew.w - sb * h0v.w;
    hv.x += STEP_F * ((o0 > 0.f) ? o0 : expm1f(o0));
    hv.y += STEP_F * ((o1 > 0.f) ? o1 : expm1f(o1));
    hv.z += STEP_F * ((o2 > 0.f) ? o2 : expm1f(o2));
    hv.w += STEP_F * ((o3 > 0.f) ? o3 : expm1f(o3));
    ((float4*)h)[(size_t)gw * 64 + lane] = hv;
}

// ---------------------------------------------------------------------------
extern "C" void kernel_launch(void* const* d_in, const int* in_sizes, int n_in,
                              void* d_out, int out_size, void* d_ws, size_t ws_size,
                              hipStream_t stream) {
    const float* x     = (const float*)d_in[0];
    const int*   ei    = (const int*)d_in[1];
    const float* enc_w = (const float*)d_in[2];
    const float* gamma = (const float*)d_in[3];
    const float* beta  = (const float*)d_in[4];
    const float* ext_w = (const float*)d_in[5];
    const float* src_b = (const float*)d_in[6];
    const float* pw_W  = (const float*)d_in[7];
    const float* l1w   = (const float*)d_in[8];
    const float* l1b   = (const float*)d_in[9];
    const float* l2w   = (const float*)d_in[10];
    const float* l2b   = (const float*)d_in[11];
    float* h = (float*)d_out;

    unsigned char* wp_ = (unsigned char*)d_ws;
    size_t off = 0;
    auto alloc = [&](size_t bytes) {
        unsigned char* p = wp_ + off;
        off += (bytes + 255) & ~(size_t)255;
        return p;
    };
    float* h0     = (float*)alloc((size_t)NNODES * 256 * 4);
    u16*   outp   = (u16*)  alloc((size_t)NNODES * 256 * 2);   // also lin1 scratch
    u16*   encbf  = (u16*)  alloc((size_t)256 * KENC * 2);
    u16*   wpbf   = (u16*)  alloc(65536 * 2);
    u16*   w1bf   = (u16*)  alloc(65536 * 2);
    u16*   w2bf   = (u16*)  alloc(65536 * 2);
    int*   deg    = (int*)  alloc((size_t)NNODES * 4);
    float* dinv   = (float*)alloc((size_t)NNODES * 4);
    int*   rowptr = (int*)  alloc((size_t)(NNODES + 1) * 4);
    int*   fillp  = (int*)  alloc((size_t)NNODES * 4);
    int2*  edges  = (int2*) alloc((size_t)NEDGE * 8);
    int*   bsum   = (int*)  alloc((size_t)NB1 * 4);
    float* sums   = (float*)alloc(512 * 4);
    float* ss     = (float*)alloc(512 * 4);

    hipMemsetAsync(deg, 0, (size_t)NNODES * 4, stream);
    hipMemsetAsync(sums, 0, 512 * 4, stream);

    conv_encw<<<(256 * KENC) / 256, 256, 0, stream>>>(enc_w, encbf);
    conv_w256<<<512, 256, 0, stream>>>(l1w, l2w, w1bf, w2bf);
    make_wp<<<256, 256, 0, stream>>>(pw_W, wpbf);
    count_deg<<<(NEDGE + 255) / 256, 256, 0, stream>>>(ei, deg);
    scan_pass1<<<NB1, 256, 0, stream>>>(deg, bsum);
    scan_pass2<<<1, 512, 0, stream>>>(bsum);
    scan_pass3<<<NB1, 256, 0, stream>>>(deg, bsum, rowptr, fillp, dinv);
    fill_csr<<<(NEDGE + 255) / 256, 256, 0, stream>>>(ei, dinv, fillp, edges);

    const int MG = (NNODES + 127) / 128;   // 782

    // encoder: h_pre = x @ enc_w^T  (f32 store into d_out, BN stats fused)
    gemm_n256<0, 4><<<MG, 256, 0, stream>>>(x, encbf, h, sums, NNODES, FIN, KENC, KENC / 32, FIN);
    bn_final<<<1, 256, 0, stream>>>(sums, gamma, beta, ss);
    bn_apply<<<NNODES / 4, 256, 0, stream>>>(h, h0, ss);

    for (int l = 0; l < NLAYER; ++l) {
        gemm_n256<1, 1><<<MG, 256, 0, stream>>>(h, wpbf, outp, nullptr, NNODES, 256, 256, 8, 256);
        layer_agg<<<NNODES / 4, 256, 0, stream>>>(outp, rowptr, edges, ext_w, src_b, h0, h);
    }

    // lin1 (bias+elu -> bf16 scratch), lin2 (bias -> f32 out)
    gemm_n256<1, 2><<<MG, 256, 0, stream>>>(h, w1bf, outp, l1b, NNODES, 256, 256, 8, 256);
    gemm_n256<2, 3><<<MG, 256, 0, stream>>>(outp, w2bf, h, l2b, NNODES, 256, 256, 8, 256);
}

// Round 2
// 2176.804 us; speedup vs baseline: 1.1832x; 1.0151x over previous
//
#include <hip/hip_runtime.h>
#include <hip/hip_bf16.h>
#include <math.h>

#define NNODES 100000
#define FIN    2613
#define KENC   2624      // FIN padded to multiple of 32
#define HID    256
#define NEDGE  320000
#define NLAYER 4
#define STEP_F 0.1f
#define EPS_F  1e-5f
#define NB1    391       // ceil(NNODES/256) scan blocks

typedef unsigned short u16;
typedef __bf16 bf16_8 __attribute__((ext_vector_type(8)));
typedef float  f32x4v __attribute__((ext_vector_type(4)));

static __device__ __forceinline__ u16 f2bf(float f) {
    unsigned int u; __builtin_memcpy(&u, &f, 4);
    unsigned int r = (u + 0x7fffu + ((u >> 16) & 1u)) >> 16;
    return (u16)r;
}
static __device__ __forceinline__ float bf2f(u16 u) {
    unsigned int i = ((unsigned int)u) << 16;
    float f; __builtin_memcpy(&f, &i, 4);
    return f;
}

static __device__ __forceinline__ void async4(void* l, const void* g) {
    __builtin_amdgcn_global_load_lds((const __attribute__((address_space(1))) unsigned int*)g,
                                     (__attribute__((address_space(3))) unsigned int*)l, 4, 0, 0);
}
static __device__ __forceinline__ void async16(void* l, const void* g) {
    __builtin_amdgcn_global_load_lds((const __attribute__((address_space(1))) unsigned int*)g,
                                     (__attribute__((address_space(3))) unsigned int*)l, 16, 0, 0);
}

// ---------------------------------------------------------------------------
// staging helpers — all geometry compile-time; clamps stripped via template
// bools so the non-edge 781/782 blocks get pure affine addresses the
// compiler can strength-reduce (BASE + c*const + kt*const).
// ---------------------------------------------------------------------------
template<bool CR, bool CK>
static __device__ __forceinline__ void stage_a0(unsigned char* As, const float* A,
                                                int mblock, int tid, int wave, int kt) {
    const int rl   = tid >> 5;                               // row&7, const/thread
    const int ksrc = ((((tid >> 2) & 7) ^ rl) << 2) | (tid & 3);
#pragma unroll
    for (int c = 0; c < 16; ++c) {
        int grow = mblock + c * 8 + rl;
        if (CR) grow = (grow > NNODES - 1) ? NNODES - 1 : grow;
        int gk = kt * 32 + ksrc;
        if (CK) gk = (gk > FIN - 1) ? FIN - 1 : gk;
        async4(As + (size_t)(c * 256 + wave * 64) * 4,
               A + (size_t)grow * FIN + gk);
    }
}

template<bool CR>
static __device__ __forceinline__ void stage_a1(unsigned char* As, const float* A,
                                                int mblock, int tid, int wave, int kt) {
    const int r0   = tid >> 3;
    const int qsrc = (tid & 7) ^ (r0 & 7);
#pragma unroll
    for (int c = 0; c < 4; ++c) {
        int grow = mblock + c * 32 + r0;
        if (CR) grow = (grow > NNODES - 1) ? NNODES - 1 : grow;
        async16(As + (size_t)(c * 256 + wave * 64) * 16,
                A + (size_t)grow * 256 + kt * 32 + qsrc * 4);
    }
}

template<bool CR>
static __device__ __forceinline__ void stage_a2(unsigned char* As, const u16* A,
                                                int mblock, int tid, int wave, int kt) {
    const int r0   = tid >> 2;
    const int csrc = (tid & 3) ^ (r0 & 3);
#pragma unroll
    for (int c = 0; c < 2; ++c) {
        int grow = mblock + c * 64 + r0;
        if (CR) grow = (grow > NNODES - 1) ? NNODES - 1 : grow;
        async16(As + (size_t)(c * 256 + wave * 64) * 16,
                A + (size_t)grow * 256 + kt * 32 + csrc * 8);
    }
}

template<int LDB>
static __device__ __forceinline__ void stage_b(unsigned char* Bs, const u16* B,
                                               int tid, int wave, int kt) {
    const int n0   = tid >> 2;
    const int csrc = (tid & 3) ^ (n0 & 3);
#pragma unroll
    for (int c = 0; c < 4; ++c) {
        int n = c * 64 + n0;
        async16(Bs + (size_t)(c * 256 + wave * 64) * 16,
                B + (size_t)n * LDB + kt * 32 + csrc * 8);
    }
}

// ---------------------------------------------------------------------------
// GEMM: C[M x 256] = A[M x K] * B[256 x K]^T   (B given n-major, bf16)
// Tile: 128(M) x 256(N) per block, 256 threads (4 waves, each 128x64).
// STAGE: 0 = A f32 ldA=FIN (rows not 16B-aligned -> dword loads), K=KENC
//        1 = A f32 ldA=256, K=256
//        2 = A bf16 ldA=256, K=256
// MODE:  0 = store f32   1 = store bf16   2 = +bias, elu, store bf16
//        3 = +bias, store f32
//        4 = store f32 + accumulate per-column sum/sumsq into bias[0..511]
// ---------------------------------------------------------------------------
template<int STAGE, int MODE>
__global__ __launch_bounds__(256, 2) void gemm_n256(
    const void* __restrict__ Av, const u16* __restrict__ B, void* __restrict__ Cv,
    const float* __restrict__ bias)
{
    constexpr int KT     = (STAGE == 0) ? (KENC / 32) : 8;
    constexpr int LDB    = (STAGE == 0) ? KENC : 256;
    constexpr int ABYTES = (STAGE == 2) ? 8192 : 16384;
    __shared__ __align__(16) unsigned char lds[ABYTES + 16384];
    unsigned char* As = lds;
    unsigned char* Bs = lds + ABYTES;

    const int tid  = threadIdx.x;
    const int wave = tid >> 6;
    const int lane = tid & 63;
    const int mblock = blockIdx.x * 128;
    const bool edge_m = (mblock + 128 > NNODES);   // only last block

    f32x4v acc[8][4];
#pragma unroll
    for (int i = 0; i < 8; ++i)
#pragma unroll
        for (int j = 0; j < 4; ++j)
            acc[i][j] = (f32x4v){0.f, 0.f, 0.f, 0.f};

    for (int kt = 0; kt < KT; ++kt) {
        __syncthreads();
        // ---- stage A ----
        if (STAGE == 0) {
            const float* A = (const float*)Av;
            if (!edge_m) {
                if (kt < KT - 1) stage_a0<false, false>(As, A, mblock, tid, wave, kt);
                else             stage_a0<false, true >(As, A, mblock, tid, wave, kt);
            } else {
                if (kt < KT - 1) stage_a0<true,  false>(As, A, mblock, tid, wave, kt);
                else             stage_a0<true,  true >(As, A, mblock, tid, wave, kt);
            }
        } else if (STAGE == 1) {
            const float* A = (const float*)Av;
            if (!edge_m) stage_a1<false>(As, A, mblock, tid, wave, kt);
            else         stage_a1<true >(As, A, mblock, tid, wave, kt);
        } else {
            const u16* A = (const u16*)Av;
            if (!edge_m) stage_a2<false>(As, A, mblock, tid, wave, kt);
            else         stage_a2<true >(As, A, mblock, tid, wave, kt);
        }
        // ---- stage B: [256][32] bf16 ----
        stage_b<LDB>(Bs, B, tid, wave, kt);
        __syncthreads();

        // ---- compute ----
        bf16_8 bfr[4];
#pragma unroll
        for (int j = 0; j < 4; ++j) {
            int n = wave * 64 + j * 16 + (lane & 15);
            int ch = (lane >> 4) ^ (n & 3);
            bfr[j] = *(const bf16_8*)(Bs + (size_t)n * 64 + (size_t)ch * 16);
        }
#pragma unroll
        for (int i = 0; i < 8; ++i) {
            bf16_8 af;
            int row = i * 16 + (lane & 15);
            if (STAGE == 2) {
                int ch = (lane >> 4) ^ (row & 3);
                af = *(const bf16_8*)(As + (size_t)row * 64 + (size_t)ch * 16);
            } else {
                int kq0 = (lane >> 4) * 2;
                f32x4v a0 = *(const f32x4v*)(As + (size_t)row * 128 + (size_t)((kq0    ) ^ (row & 7)) * 16);
                f32x4v a1 = *(const f32x4v*)(As + (size_t)row * 128 + (size_t)((kq0 + 1) ^ (row & 7)) * 16);
                af[0] = (__bf16)a0[0]; af[1] = (__bf16)a0[1]; af[2] = (__bf16)a0[2]; af[3] = (__bf16)a0[3];
                af[4] = (__bf16)a1[0]; af[5] = (__bf16)a1[1]; af[6] = (__bf16)a1[2]; af[7] = (__bf16)a1[3];
            }
#pragma unroll
            for (int j = 0; j < 4; ++j)
                acc[i][j] = __builtin_amdgcn_mfma_f32_16x16x32_bf16(af, bfr[j], acc[i][j], 0, 0, 0);
        }
    }

    // ---- epilogue ----
#pragma unroll
    for (int j = 0; j < 4; ++j) {
        int col = wave * 64 + j * 16 + (lane & 15);
        float bv = 0.f;
        if (MODE == 2 || MODE == 3) bv = bias[col];
        float s = 0.f, q = 0.f;
#pragma unroll
        for (int i = 0; i < 8; ++i) {
            int rowb = mblock + i * 16 + ((lane >> 4) << 2);
#pragma unroll
            for (int r = 0; r < 4; ++r) {
                int row = rowb + r;
                if (row < NNODES) {
                    float v = acc[i][j][r];
                    if (MODE == 0) {
                        ((float*)Cv)[(size_t)row * 256 + col] = v;
                    } else if (MODE == 1) {
                        ((u16*)Cv)[(size_t)row * 256 + col] = f2bf(v);
                    } else if (MODE == 2) {
                        v += bv; v = (v > 0.f) ? v : expm1f(v);
                        ((u16*)Cv)[(size_t)row * 256 + col] = f2bf(v);
                    } else if (MODE == 3) {
                        ((float*)Cv)[(size_t)row * 256 + col] = v + bv;
                    } else {
                        ((float*)Cv)[(size_t)row * 256 + col] = v;
                        s += v; q += v * v;
                    }
                }
            }
        }
        if (MODE == 4) {
            // lanes {l, l^16, l^32, l^48} hold the 4 row-group partials of col
            s += __shfl_xor(s, 16, 64); s += __shfl_xor(s, 32, 64);
            q += __shfl_xor(q, 16, 64); q += __shfl_xor(q, 32, 64);
            if ((lane & 48) == 0) {
                atomicAdd(const_cast<float*>(&bias[col]),       s);
                atomicAdd(const_cast<float*>(&bias[col + 256]), q);
            }
        }
    }
}

// ---------------------------------------------------------------------------
// small prep kernels
// ---------------------------------------------------------------------------
__global__ void conv_encw(const float* __restrict__ w, u16* __restrict__ o) {
    int i = blockIdx.x * 256 + threadIdx.x;      // over 256*KENC
    int n = i / KENC, k = i - n * KENC;
    float v = (k < FIN) ? w[(size_t)n * FIN + k] : 0.f;
    o[i] = f2bf(v);
}

__global__ void conv_w256(const float* __restrict__ w1, const float* __restrict__ w2,
                          u16* __restrict__ o1, u16* __restrict__ o2) {
    int i = blockIdx.x * 256 + threadIdx.x;      // 512 blocks
    if (i < 65536) o1[i] = f2bf(w1[i]);
    else           o2[i - 65536] = f2bf(w2[i - 65536]);
}

// one row per block, 256 blocks
__global__ void make_wp(const float* __restrict__ pw, u16* __restrict__ wp) {
    const int i = blockIdx.x;
    const int j = threadIdx.x;
    const int lane = j & 63, wid = j >> 6;
    __shared__ float ws4[4];
    __shared__ float ssum;
    float w0;
    if (i < j)      w0 = pw[i * 258 + j];
    else if (i > j) w0 = pw[j * 258 + i];
    else            w0 = 0.f;
    float a = fabsf(w0);
#pragma unroll
    for (int off = 32; off > 0; off >>= 1) a += __shfl_xor(a, off, 64);
    if (lane == 0) ws4[wid] = a;
    __syncthreads();
    if (j == 0) ssum = ws4[0] + ws4[1] + ws4[2] + ws4[3];
    __syncthreads();
    if (j != i) {
        wp[i * 256 + j] = f2bf(w0);
    } else {
        float q = pw[i * 258 + 256];
        float r = pw[i * 258 + 257];
        wp[i * 256 + i] = f2bf(q * ssum + r);
    }
}

__global__ void count_deg(const int* __restrict__ ei, int* __restrict__ deg) {
    int e = blockIdx.x * 256 + threadIdx.x;
    if (e < NEDGE) atomicAdd(&deg[ei[NEDGE + e]], 1);
}

// ---- parallel 3-phase scan over deg ----
__global__ void scan_pass1(const int* __restrict__ deg, int* __restrict__ bsum) {
    __shared__ int ws4[4];
    const int t = threadIdx.x, lane = t & 63, wid = t >> 6;
    int i = blockIdx.x * 256 + t;
    int v = (i < NNODES) ? deg[i] : 0;
#pragma unroll
    for (int off = 32; off > 0; off >>= 1) v += __shfl_xor(v, off, 64);
    if (lane == 0) ws4[wid] = v;
    __syncthreads();
    if (t == 0) bsum[blockIdx.x] = ws4[0] + ws4[1] + ws4[2] + ws4[3];
}

__global__ void scan_pass2(int* __restrict__ bsum) {   // 1 block, 512 threads
    __shared__ int wsum[8];
    const int t = threadIdx.x, lane = t & 63, wid = t >> 6;
    int v = (t < NB1) ? bsum[t] : 0;
    int s = v;
#pragma unroll
    for (int off = 1; off < 64; off <<= 1) {
        int x = __shfl_up(s, off, 64);
        if (lane >= off) s += x;
    }
    if (lane == 63) wsum[wid] = s;
    __syncthreads();
    int woff = 0;
    for (int w = 0; w < wid; ++w) woff += wsum[w];
    if (t < NB1) bsum[t] = woff + s;                    // inclusive block sums
}

__global__ void scan_pass3(const int* __restrict__ deg, const int* __restrict__ bsum,
                           int* __restrict__ rowptr, int* __restrict__ fillp,
                           float* __restrict__ dinv) {
    __shared__ int wsum[4];
    const int b = blockIdx.x, t = threadIdx.x, lane = t & 63, wid = t >> 6;
    int i = b * 256 + t;
    int v = (i < NNODES) ? deg[i] : 0;
    int s = v;
#pragma unroll
    for (int off = 1; off < 64; off <<= 1) {
        int x = __shfl_up(s, off, 64);
        if (lane >= off) s += x;
    }
    if (lane == 63) wsum[wid] = s;
    __syncthreads();
    int woff = 0;
    for (int w = 0; w < wid; ++w) woff += wsum[w];
    int off0 = (b > 0) ? bsum[b - 1] : 0;
    int incl = off0 + woff + s;
    if (i < NNODES) {
        rowptr[i + 1] = incl;
        fillp[i]      = incl - v;                       // exclusive = rowptr[i]
        dinv[i]       = (v > 0) ? (1.0f / sqrtf((float)v)) : 0.f;
    }
    if (b == 0 && t == 0) rowptr[0] = 0;
}

// edges interleaved: {src_node, bits(norm_weight)} — one 8B record per edge
__global__ void fill_csr(const int* __restrict__ ei, const float* __restrict__ dinv,
                         int* __restrict__ fillpos, int2* __restrict__ edges) {
    int e = blockIdx.x * 256 + threadIdx.x;
    if (e < NEDGE) {
        int r = ei[e], c = ei[NEDGE + e];
        int pos = atomicAdd(&fillpos[c], 1);
        edges[pos] = make_int2(r, __float_as_int(dinv[r] * dinv[c]));
    }
}

// ---------------------------------------------------------------------------
// batchnorm finish + apply (stats fused into encoder GEMM epilogue).
// bn_apply also emits g0 = src_b * h0 in bf16 — the layer-invariant source
// term, halving that stream's bytes for all 4 layer_agg reads.
// ---------------------------------------------------------------------------
__global__ void bn_final(const float* __restrict__ sums, const float* __restrict__ gamma,
                         const float* __restrict__ beta, float* __restrict__ ss) {
    int c = threadIdx.x;
    float mean = sums[c] * (1.f / NNODES);
    float var  = sums[256 + c] * (1.f / NNODES) - mean * mean;
    float sc   = gamma[c] / sqrtf(var + EPS_F);
    ss[c] = sc;
    ss[256 + c] = beta[c] - mean * sc;
}

__global__ void bn_apply(float* __restrict__ h, u16* __restrict__ g0,
                         const float* __restrict__ ss, const float* __restrict__ srcb) {
    size_t i = (size_t)blockIdx.x * 256 + threadIdx.x;   // float4 group
    int cg = (int)(i & 63);
    float4 v  = ((const float4*)h)[i];
    float4 sc = ((const float4*)ss)[cg];
    float4 sh = ((const float4*)(ss + 256))[cg];
    v.x = v.x * sc.x + sh.x;
    v.y = v.y * sc.y + sh.y;
    v.z = v.z * sc.z + sh.z;
    v.w = v.w * sc.w + sh.w;
    ((float4*)h)[i] = v;
    float sb = srcb[0];
    ushort4 g;
    g.x = f2bf(sb * v.x);
    g.y = f2bf(sb * v.y);
    g.z = f2bf(sb * v.z);
    g.w = f2bf(sb * v.w);
    ((ushort4*)g0)[i] = g;
}

// ---------------------------------------------------------------------------
// graph aggregation + GRAFF update (one wave per node)
// ---------------------------------------------------------------------------
__global__ void layer_agg(const u16* __restrict__ outp, const int* __restrict__ rowptr,
                          const int2* __restrict__ edges,
                          const float* __restrict__ extw, const u16* __restrict__ g0,
                          float* __restrict__ h) {
    int gw   = (blockIdx.x * 256 + threadIdx.x) >> 6;    // node id
    int lane = threadIdx.x & 63;
    if (gw >= NNODES) return;
    int beg = rowptr[gw], end = rowptr[gw + 1];
    int n   = end - beg;
    float a0 = 0.f, a1 = 0.f, a2 = 0.f, a3 = 0.f;
    if (n <= 64) {
        int2 e = (lane < n) ? edges[beg + lane] : make_int2(0, 0);
        for (int k = 0; k < n; ++k) {
            int   s = __shfl(e.x, k, 64);
            float w = __int_as_float(__shfl(e.y, k, 64));
            ushort4 u = ((const ushort4*)(outp + (size_t)s * 256))[lane];
            a0 += w * bf2f(u.x);
            a1 += w * bf2f(u.y);
            a2 += w * bf2f(u.z);
            a3 += w * bf2f(u.w);
        }
    } else {
        for (int i = beg; i < end; ++i) {
            int2 e = edges[i];
            float w = __int_as_float(e.y);
            ushort4 u = ((const ushort4*)(outp + (size_t)e.x * 256))[lane];
            a0 += w * bf2f(u.x);
            a1 += w * bf2f(u.y);
            a2 += w * bf2f(u.z);
            a3 += w * bf2f(u.w);
        }
    }
    float4  hv = ((const float4*)h)[(size_t)gw * 64 + lane];
    ushort4 gv = ((const ushort4*)g0)[(size_t)gw * 64 + lane];
    float4  ew = ((const float4*)extw)[lane];
    float o0 = a0 - hv.x * ew.x - bf2f(gv.x);
    float o1 = a1 - hv.y * ew.y - bf2f(gv.y);
    float o2 = a2 - hv.z * ew.z - bf2f(gv.z);
    float o3 = a3 - hv.w * ew.w - bf2f(gv.w);
    hv.x += STEP_F * ((o0 > 0.f) ? o0 : expm1f(o0));
    hv.y += STEP_F * ((o1 > 0.f) ? o1 : expm1f(o1));
    hv.z += STEP_F * ((o2 > 0.f) ? o2 : expm1f(o2));
    hv.w += STEP_F * ((o3 > 0.f) ? o3 : expm1f(o3));
    ((float4*)h)[(size_t)gw * 64 + lane] = hv;
}

// ---------------------------------------------------------------------------
extern "C" void kernel_launch(void* const* d_in, const int* in_sizes, int n_in,
                              void* d_out, int out_size, void* d_ws, size_t ws_size,
                              hipStream_t stream) {
    const float* x     = (const float*)d_in[0];
    const int*   ei    = (const int*)d_in[1];
    const float* enc_w = (const float*)d_in[2];
    const float* gamma = (const float*)d_in[3];
    const float* beta  = (const float*)d_in[4];
    const float* ext_w = (const float*)d_in[5];
    const float* src_b = (const float*)d_in[6];
    const float* pw_W  = (const float*)d_in[7];
    const float* l1w   = (const float*)d_in[8];
    const float* l1b   = (const float*)d_in[9];
    const float* l2w   = (const float*)d_in[10];
    const float* l2b   = (const float*)d_in[11];
    float* h = (float*)d_out;

    unsigned char* wp_ = (unsigned char*)d_ws;
    size_t off = 0;
    auto alloc = [&](size_t bytes) {
        unsigned char* p = wp_ + off;
        off += (bytes + 255) & ~(size_t)255;
        return p;
    };
    u16*   g0     = (u16*)  alloc((size_t)NNODES * 256 * 2);   // src_b * h0, bf16
    u16*   outp   = (u16*)  alloc((size_t)NNODES * 256 * 2);   // also lin1 scratch
    u16*   encbf  = (u16*)  alloc((size_t)256 * KENC * 2);
    u16*   wpbf   = (u16*)  alloc(65536 * 2);
    u16*   w1bf   = (u16*)  alloc(65536 * 2);
    u16*   w2bf   = (u16*)  alloc(65536 * 2);
    int*   deg    = (int*)  alloc((size_t)NNODES * 4);
    float* dinv   = (float*)alloc((size_t)NNODES * 4);
    int*   rowptr = (int*)  alloc((size_t)(NNODES + 1) * 4);
    int*   fillp  = (int*)  alloc((size_t)NNODES * 4);
    int2*  edges  = (int2*) alloc((size_t)NEDGE * 8);
    int*   bsum   = (int*)  alloc((size_t)NB1 * 4);
    float* sums   = (float*)alloc(512 * 4);
    float* ss     = (float*)alloc(512 * 4);

    hipMemsetAsync(deg, 0, (size_t)NNODES * 4, stream);
    hipMemsetAsync(sums, 0, 512 * 4, stream);

    conv_encw<<<(256 * KENC) / 256, 256, 0, stream>>>(enc_w, encbf);
    conv_w256<<<512, 256, 0, stream>>>(l1w, l2w, w1bf, w2bf);
    make_wp<<<256, 256, 0, stream>>>(pw_W, wpbf);
    count_deg<<<(NEDGE + 255) / 256, 256, 0, stream>>>(ei, deg);
    scan_pass1<<<NB1, 256, 0, stream>>>(deg, bsum);
    scan_pass2<<<1, 512, 0, stream>>>(bsum);
    scan_pass3<<<NB1, 256, 0, stream>>>(deg, bsum, rowptr, fillp, dinv);
    fill_csr<<<(NEDGE + 255) / 256, 256, 0, stream>>>(ei, dinv, fillp, edges);

    const int MG = (NNODES + 127) / 128;   // 782

    // encoder: h_pre = x @ enc_w^T  (f32 store into d_out, BN stats fused)
    gemm_n256<0, 4><<<MG, 256, 0, stream>>>(x, encbf, h, sums);
    bn_final<<<1, 256, 0, stream>>>(sums, gamma, beta, ss);
    bn_apply<<<NNODES / 4, 256, 0, stream>>>(h, g0, ss, src_b);

    for (int l = 0; l < NLAYER; ++l) {
        gemm_n256<1, 1><<<MG, 256, 0, stream>>>(h, wpbf, outp, nullptr);
        layer_agg<<<NNODES / 4, 256, 0, stream>>>(outp, rowptr, edges, ext_w, g0, h);
    }

    // lin1 (bias+elu -> bf16 scratch), lin2 (bias -> f32 out)
    gemm_n256<1, 2><<<MG, 256, 0, stream>>>(h, w1bf, outp, l1b);
    gemm_n256<2, 3><<<MG, 256, 0, stream>>>(outp, w2bf, h, l2b);
}